// Round 2
// baseline (320.235 us; speedup 1.0000x reference)
//
#include <hip/hip_runtime.h>
#include <hip/hip_bf16.h>
#include <stdint.h>

// Problem constants (reference: B, L, H = 64, 512, 1024)
#define BB 64
#define LL 512
#define HH 1024

using short8 = __attribute__((ext_vector_type(8))) short;
using f32x4  = __attribute__((ext_vector_type(4))) float;

static __device__ __forceinline__ unsigned short f2b(float x) {
    union { float f; uint32_t u; } t; t.f = x;
    uint32_t u = t.u;
    u += 0x7fffu + ((u >> 16) & 1u);   // round-to-nearest-even
    return (unsigned short)(u >> 16);
}

// ---------------------------------------------------------------------------
// Meta kernel: 3 blocks, one per category.
// Semantics (verified against reference):
//  - PLM mask (B,L): contiguous span per example; r-th True (row-major) is
//    global subword r. ex_sub_off = per-example exclusive token counts.
//  - word mask (NI, WmaxI) with UNKNOWN row structure on host: k-th True
//    (flat, row-major) is global word k; pooled word k is scattered to flat
//    row position of that True, offset by the category's output row base.
//  - subword mask (NW, Smax): row w has ns_w leading Trues; Smax = size/NW.
// Outputs per word slot:
//   g_src[w]  = flat token index (i*L + pos) of word w's first subword
//   g_ns[w]   = subword count
//   g_orow[w] = global output row (or -1 for padding slots)
// ---------------------------------------------------------------------------
__global__ __launch_bounds__(256)
void meta_kernel(const int* __restrict__ plm0, const int* __restrict__ plm1,
                 const int* __restrict__ plm2,
                 const int* __restrict__ sub0, const int* __restrict__ sub1,
                 const int* __restrict__ sub2,
                 const int* __restrict__ wm0, const int* __restrict__ wm1,
                 const int* __restrict__ wm2,
                 int ssub0, int ssub1, int ssub2,
                 int wmsz0, int wmsz1, int wmsz2,
                 int cap0, int cap1, int cap2,
                 int* __restrict__ g_src, int* __restrict__ g_ns,
                 int* __restrict__ g_orow)
{
    const int cat = blockIdx.x;
    const int* P    = (cat == 0) ? plm0 : (cat == 1) ? plm1 : plm2;
    const int* D    = (cat == 0) ? sub0 : (cat == 1) ? sub1 : sub2;
    const int* WM   = (cat == 0) ? wm0  : (cat == 1) ? wm1  : wm2;
    const int ssub  = (cat == 0) ? ssub0 : (cat == 1) ? ssub1 : ssub2;
    const int wmsz  = (cat == 0) ? wmsz0 : (cat == 1) ? wmsz1 : wmsz2;
    const int cap   = (cat == 0) ? cap0  : (cat == 1) ? cap1  : cap2;
    int wb = 0, rbase = 0;
    if (cat >= 1) { wb += cap0; rbase += wmsz0; }
    if (cat >= 2) { wb += cap1; rbase += wmsz1; }

    __shared__ int ex_f[BB], ex_cnt[BB];
    __shared__ int ex_sub_off[BB + 1];
    __shared__ int scanbuf[256];
    __shared__ int carry_sh;
    __shared__ int NW_sh;

    const int tid = threadIdx.x;

    // Per-example: first True index + count of PLM mask (contiguous span).
    if (tid < BB) {
        const int* row = P + tid * LL;
        int f = -1, c = 0;
        for (int k = 0; k < LL; ++k) {
            int v = row[k];
            if (v) { ++c; if (f < 0) f = k; }
        }
        ex_f[tid] = (f < 0) ? 0 : f;
        ex_cnt[tid] = c;
    }
    __syncthreads();
    if (tid == 0) {
        int s = 0;
        for (int i = 0; i < BB; ++i) { ex_sub_off[i] = s; s += ex_cnt[i]; }
        ex_sub_off[BB] = s;
        carry_sh = 0;
    }
    __syncthreads();

    // ---- Pass A: flat scan over word mask -> g_orow (k-th True -> flat pos)
    for (int base = 0; base < wmsz; base += 256) {
        const int p = base + tid;
        const int v = (p < wmsz) ? (WM[p] != 0) : 0;
        scanbuf[tid] = v;
        __syncthreads();
        for (int off = 1; off < 256; off <<= 1) {
            int x = (tid >= off) ? scanbuf[tid - off] : 0;
            __syncthreads();
            scanbuf[tid] += x;
            __syncthreads();
        }
        const int k = carry_sh + scanbuf[tid] - v;   // exclusive rank
        if (v) g_orow[wb + k] = rbase + p;
        __syncthreads();
        if (tid == 255) carry_sh += scanbuf[255];
        __syncthreads();
    }
    if (tid == 0) { NW_sh = carry_sh; carry_sh = 0; }
    __syncthreads();
    const int NW = NW_sh;
    const int Smax = (NW > 0) ? (ssub / NW) : 1;   // subword mask row stride

    // Padding slots (no syncs inside — safe anywhere).
    for (int k = NW + tid; k < cap; k += 256) {
        g_orow[wb + k] = -1;
        g_ns[wb + k] = 0;
        g_src[wb + k] = 0;
    }

    // ---- Pass B: chunked scan over per-word subword counts -> g_src, g_ns
    for (int base = 0; base < NW; base += 256) {
        const int w = base + tid;
        int ns = 0;
        if (w < NW) {
            const int* dr = D + (size_t)w * Smax;
            for (int j = 0; j < Smax; ++j) ns += (dr[j] != 0);
        }
        scanbuf[tid] = ns;
        __syncthreads();
        for (int off = 1; off < 256; off <<= 1) {
            int x = (tid >= off) ? scanbuf[tid - off] : 0;
            __syncthreads();
            scanbuf[tid] += x;
            __syncthreads();
        }
        const int subrank = carry_sh + scanbuf[tid] - ns;  // global subword rank
        if (w < NW) {
            // find example i with ex_sub_off[i] <= subrank < ex_sub_off[i+1]
            int lo = 0, hi = BB;
            while (hi - lo > 1) {
                int mid = (lo + hi) >> 1;
                if (ex_sub_off[mid] <= subrank) lo = mid; else hi = mid;
            }
            const int i = lo;
            const int gw = wb + w;
            g_src[gw] = i * LL + ex_f[i] + (subrank - ex_sub_off[i]);
            g_ns[gw]  = ns;
        }
        __syncthreads();
        if (tid == 255) carry_sh += scanbuf[255];
        __syncthreads();
    }
}

// ---------------------------------------------------------------------------
// Means kernel: one block per word slot; mean over ns consecutive token rows,
// emit bf16 row into meansB.
// ---------------------------------------------------------------------------
__global__ __launch_bounds__(256)
void means_kernel(const float* __restrict__ X, const int* __restrict__ g_src,
                  const int* __restrict__ g_ns, const int* __restrict__ g_orow,
                  unsigned short* __restrict__ meansB)
{
    const int w = blockIdx.x;
    if (g_orow[w] < 0) return;
    const int ns = g_ns[w];
    const int base = g_src[w];
    const int c0 = threadIdx.x * 4;
    float ax = 0.f, ay = 0.f, az = 0.f, aw = 0.f;
    for (int j = 0; j < ns; ++j) {
        const float4 v = *reinterpret_cast<const float4*>(
            X + (size_t)(base + j) * HH + c0);
        ax += v.x; ay += v.y; az += v.z; aw += v.w;
    }
    const float s = 1.0f / (float)ns;
    ushort4 o;
    o.x = f2b(ax * s); o.y = f2b(ay * s); o.z = f2b(az * s); o.w = f2b(aw * s);
    *reinterpret_cast<ushort4*>(meansB + (size_t)w * HH + c0) = o;
}

// ---------------------------------------------------------------------------
// W fp32 -> bf16 conversion (row-major H x H).
// ---------------------------------------------------------------------------
__global__ __launch_bounds__(256)
void wconv_kernel(const float* __restrict__ Wf, unsigned short* __restrict__ Wb)
{
    const int idx = (blockIdx.x * 256 + threadIdx.x) * 4;
    const float4 v = *reinterpret_cast<const float4*>(Wf + idx);
    ushort4 o;
    o.x = f2b(v.x); o.y = f2b(v.y); o.z = f2b(v.z); o.w = f2b(v.w);
    *reinterpret_cast<ushort4*>(Wb + idx) = o;
}

// ---------------------------------------------------------------------------
// GEMM: C[w, o] = tanh( sum_h mean[w,h] * W[o,h] + b[o] ), scattered to
// out[g_orow[w], :]. Block = 256 thr = 4 waves; block tile 64(M) x 64(N);
// each wave does 16 M-rows x 64 N-cols via 4 mfma_f32_16x16x32_bf16 accs.
// B-tile (64x32 bf16) staged in LDS (stride 40 elems = 80 B, 16B-aligned).
// ---------------------------------------------------------------------------
__global__ __launch_bounds__(256)
void gemm_kernel(const unsigned short* __restrict__ A,
                 const unsigned short* __restrict__ Wb,
                 const float* __restrict__ bias,
                 const int* __restrict__ g_orow,
                 float* __restrict__ out, int M_total)
{
    __shared__ unsigned short lb[64 * 40];

    const int m_base = blockIdx.x * 64;
    const int n_base = blockIdx.y * 64;
    const int tid = threadIdx.x;
    const int wv = tid >> 6;
    const int lane = tid & 63;
    const int q = lane >> 4;     // quad id 0..3
    const int ml = lane & 15;

    const int row16 = m_base + wv * 16 + ml;
    const int orow_ml = (row16 < M_total) ? g_orow[row16] : -1;
    if (!__syncthreads_or(orow_ml >= 0)) return;   // whole 64-row stripe padded

    f32x4 acc[4];
    #pragma unroll
    for (int t = 0; t < 4; ++t) acc[t] = (f32x4){0.f, 0.f, 0.f, 0.f};

    // staging indices: thread -> (row 0..63, 8-elem chunk 0..3)
    const int lrow = tid >> 2;
    const int lq = tid & 3;
    const unsigned short* Bsrc = Wb + (size_t)(n_base + lrow) * HH + lq * 8;
    unsigned short* Bdst = lb + lrow * 40 + lq * 8;

    const unsigned short* Ap = A + (size_t)row16 * HH + q * 8;
    const unsigned short* l0 = lb + ml * 40 + q * 8;

    for (int k0 = 0; k0 < HH; k0 += 32) {
        __syncthreads();
        *reinterpret_cast<short8*>(Bdst) =
            *reinterpret_cast<const short8*>(Bsrc + k0);
        __syncthreads();
        const short8 a  = *reinterpret_cast<const short8*>(Ap + k0);
        const short8 b0 = *reinterpret_cast<const short8*>(l0);
        const short8 b1 = *reinterpret_cast<const short8*>(l0 + 16 * 40);
        const short8 b2 = *reinterpret_cast<const short8*>(l0 + 32 * 40);
        const short8 b3 = *reinterpret_cast<const short8*>(l0 + 48 * 40);
        acc[0] = __builtin_amdgcn_mfma_f32_16x16x32_bf16(a, b0, acc[0], 0, 0, 0);
        acc[1] = __builtin_amdgcn_mfma_f32_16x16x32_bf16(a, b1, acc[1], 0, 0, 0);
        acc[2] = __builtin_amdgcn_mfma_f32_16x16x32_bf16(a, b2, acc[2], 0, 0, 0);
        acc[3] = __builtin_amdgcn_mfma_f32_16x16x32_bf16(a, b3, acc[3], 0, 0, 0);
    }

    // Epilogue: C/D layout col = lane&15, row = quad*4 + reg.
    #pragma unroll
    for (int t = 0; t < 4; ++t) {
        const int col = n_base + t * 16 + ml;
        const float bv = bias[col];
        #pragma unroll
        for (int r = 0; r < 4; ++r) {
            const int row = m_base + wv * 16 + q * 4 + r;
            if (row < M_total) {
                const int orow = g_orow[row];
                if (orow >= 0) {
                    out[(size_t)orow * HH + col] = tanhf(acc[t][r] + bv);
                }
            }
        }
    }
}

// ---------------------------------------------------------------------------
// Host launch
// Input order: 0..2 plm masks (B,L); 3..5 subword masks (NW,Smax);
// 6..8 word masks (NI,WmaxI); 9 inputs (B,L,H) f32; 10 W (H,H) f32;
// 11 b (H,) f32. Output: concat of three (NI,WmaxI,H) f32 tensors.
// ---------------------------------------------------------------------------
extern "C" void kernel_launch(void* const* d_in, const int* in_sizes, int n_in,
                              void* d_out, int out_size, void* d_ws, size_t ws_size,
                              hipStream_t stream)
{
    const int* plm0 = (const int*)d_in[0];
    const int* plm1 = (const int*)d_in[1];
    const int* plm2 = (const int*)d_in[2];
    const int* sub0 = (const int*)d_in[3];
    const int* sub1 = (const int*)d_in[4];
    const int* sub2 = (const int*)d_in[5];
    const int* wm0  = (const int*)d_in[6];
    const int* wm1  = (const int*)d_in[7];
    const int* wm2  = (const int*)d_in[8];
    const float* X    = (const float*)d_in[9];
    const float* Wf   = (const float*)d_in[10];
    const float* bias = (const float*)d_in[11];

    const int wmsz0 = in_sizes[6], wmsz1 = in_sizes[7], wmsz2 = in_sizes[8];
    const int cap0 = (wmsz0 + 63) & ~63;
    const int cap1 = (wmsz1 + 63) & ~63;
    const int cap2 = (wmsz2 + 63) & ~63;
    const int Mslots = cap0 + cap1 + cap2;   // multiple of 64
    const int gx = Mslots / 64;

    char* ws = (char*)d_ws;
    unsigned short* Wb = (unsigned short*)ws;                       // 2 MB
    unsigned short* meansB = (unsigned short*)(ws + (size_t)HH * HH * 2);
    char* p = ws + (size_t)HH * HH * 2 + (size_t)Mslots * HH * 2;
    int* g_src  = (int*)p; p += (size_t)Mslots * 4;
    int* g_ns   = (int*)p; p += (size_t)Mslots * 4;
    int* g_orow = (int*)p;

    hipMemsetAsync(d_out, 0, (size_t)out_size * sizeof(float), stream);

    wconv_kernel<<<(HH * HH / 4) / 256, 256, 0, stream>>>(Wf, Wb);

    meta_kernel<<<3, 256, 0, stream>>>(plm0, plm1, plm2, sub0, sub1, sub2,
                                       wm0, wm1, wm2,
                                       in_sizes[3], in_sizes[4], in_sizes[5],
                                       wmsz0, wmsz1, wmsz2,
                                       cap0, cap1, cap2,
                                       g_src, g_ns, g_orow);

    means_kernel<<<Mslots, 256, 0, stream>>>(X, g_src, g_ns, g_orow, meansB);

    gemm_kernel<<<dim3(gx, 16), 256, 0, stream>>>(meansB, Wb, bias, g_orow,
                                                  (float*)d_out, Mslots);
}

// Round 3
// 281.170 us; speedup vs baseline: 1.1389x; 1.1389x over previous
//
#include <hip/hip_runtime.h>
#include <hip/hip_bf16.h>
#include <stdint.h>

// Problem constants (reference: B, L, H = 64, 512, 1024)
#define BB 64
#define LL 512
#define HH 1024

using short8 = __attribute__((ext_vector_type(8))) short;
using f32x4  = __attribute__((ext_vector_type(4))) float;

static __device__ __forceinline__ unsigned short f2b(float x) {
    union { float f; uint32_t u; } t; t.f = x;
    uint32_t u = t.u;
    u += 0x7fffu + ((u >> 16) & 1u);   // round-to-nearest-even
    return (unsigned short)(u >> 16);
}

// ---------------------------------------------------------------------------
// Meta kernel v2: 3 blocks, one per category. Wave-shfl scans, ~8 barriers
// total (v1 had ~1300 — it was the latency whale).
// Semantics:
//  - PLM mask (B,L): contiguous span per example; r-th True (row-major) is
//    global subword r.
//  - word mask (flat size wmsz): k-th True -> pooled word k scatters to flat
//    position p (+rbase).
//  - subword mask (NW,Smax): row w has ns_w leading Trues; Smax = ssub/NW.
// Outputs per word slot w (base wb, capacity cap):
//   g_src[w]=first-subword flat token idx; g_ns[w]=count; g_orow[w]=out row/-1
// ---------------------------------------------------------------------------
__global__ __launch_bounds__(256)
void meta_kernel(const int* __restrict__ plm0, const int* __restrict__ plm1,
                 const int* __restrict__ plm2,
                 const int* __restrict__ sub0, const int* __restrict__ sub1,
                 const int* __restrict__ sub2,
                 const int* __restrict__ wm0, const int* __restrict__ wm1,
                 const int* __restrict__ wm2,
                 int ssub0, int ssub1, int ssub2,
                 int wmsz0, int wmsz1, int wmsz2,
                 int cap0, int cap1, int cap2,
                 int* __restrict__ g_src, int* __restrict__ g_ns,
                 int* __restrict__ g_orow)
{
    const int cat = blockIdx.x;
    const int* P    = (cat == 0) ? plm0 : (cat == 1) ? plm1 : plm2;
    const int* D    = (cat == 0) ? sub0 : (cat == 1) ? sub1 : sub2;
    const int* WM   = (cat == 0) ? wm0  : (cat == 1) ? wm1  : wm2;
    const int ssub  = (cat == 0) ? ssub0 : (cat == 1) ? ssub1 : ssub2;
    const int wmsz  = (cat == 0) ? wmsz0 : (cat == 1) ? wmsz1 : wmsz2;
    const int cap   = (cat == 0) ? cap0  : (cat == 1) ? cap1  : cap2;
    int wb = 0, rbase = 0;
    if (cat >= 1) { wb += cap0; rbase += wmsz0; }
    if (cat >= 2) { wb += cap1; rbase += wmsz1; }

    __shared__ int ex_f[BB];
    __shared__ int ex_sub_off[BB + 1];
    __shared__ int qf[256], qc[256];
    __shared__ int wsum[4];

    const int tid = threadIdx.x;
    const int lane = tid & 63;
    const int wv = tid >> 6;

    // ---- Stage 1: PLM per-example first-True + count; (row, quarter) split.
    {
        const int row = tid & 63;
        const int quarter = tid >> 6;
        const int4* rp = reinterpret_cast<const int4*>(P + row * LL + quarter * 128);
        int c = 0, f = 0x7fffffff;
        #pragma unroll 8
        for (int i = 0; i < 32; ++i) {
            int4 v = rp[i];
            if (v.x) { ++c; if (f == 0x7fffffff) f = quarter * 128 + i * 4 + 0; }
            if (v.y) { ++c; if (f == 0x7fffffff) f = quarter * 128 + i * 4 + 1; }
            if (v.z) { ++c; if (f == 0x7fffffff) f = quarter * 128 + i * 4 + 2; }
            if (v.w) { ++c; if (f == 0x7fffffff) f = quarter * 128 + i * 4 + 3; }
        }
        qc[tid] = c;
        qf[tid] = f;
    }
    __syncthreads();
    if (tid < 64) {   // wave 0 only
        int c = qc[tid] + qc[tid + 64] + qc[tid + 128] + qc[tid + 192];
        int f = min(min(qf[tid], qf[tid + 64]), min(qf[tid + 128], qf[tid + 192]));
        ex_f[tid] = (f == 0x7fffffff) ? 0 : f;
        int v = c;
        #pragma unroll
        for (int off = 1; off < 64; off <<= 1) {
            int u = __shfl_up(v, off, 64);
            if (tid >= off) v += u;
        }
        ex_sub_off[tid + 1] = v;
        if (tid == 0) ex_sub_off[0] = 0;
    }
    __syncthreads();

    // ---- Pass A: word-mask flat scan -> g_orow. Thread-contiguous segments.
    const int seg = (wmsz + 255) >> 8;
    const int p0 = tid * seg;
    const int p1 = min(p0 + seg, wmsz);
    int c = 0;
    for (int p = p0; p < p1; ++p) c += (WM[p] != 0);
    int incl = c;
    #pragma unroll
    for (int off = 1; off < 64; off <<= 1) {
        int u = __shfl_up(incl, off, 64);
        if (lane >= off) incl += u;
    }
    if (lane == 63) wsum[wv] = incl;
    __syncthreads();
    int woff = 0;
    for (int i = 0; i < wv; ++i) woff += wsum[i];
    const int NW = wsum[0] + wsum[1] + wsum[2] + wsum[3];
    int k = woff + incl - c;      // exclusive rank of first True in my segment
    for (int p = p0; p < p1; ++p)
        if (WM[p]) g_orow[wb + (k++)] = rbase + p;

    // Padding slots
    for (int w = NW + tid; w < cap; w += 256) {
        g_orow[wb + w] = -1;
        g_ns[wb + w] = 0;
        g_src[wb + w] = 0;
    }

    const int Smax = (NW > 0) ? (ssub / NW) : 1;

    // ---- Pass B: per-word subword counts -> g_src, g_ns.
    const int seg2 = (NW + 255) >> 8;
    const int w0 = tid * seg2;
    const int w1 = min(w0 + seg2, NW);
    int cs = 0;
    for (int w = w0; w < w1; ++w) {
        const int* dr = D + (size_t)w * Smax;
        for (int j = 0; j < Smax; ++j) cs += (dr[j] != 0);
    }
    __syncthreads();              // wsum reuse: all Pass-A reads are done
    int incl2 = cs;
    #pragma unroll
    for (int off = 1; off < 64; off <<= 1) {
        int u = __shfl_up(incl2, off, 64);
        if (lane >= off) incl2 += u;
    }
    if (lane == 63) wsum[wv] = incl2;
    __syncthreads();
    int soff = 0;
    for (int i = 0; i < wv; ++i) soff += wsum[i];
    int subrank = soff + incl2 - cs;
    for (int w = w0; w < w1; ++w) {
        int ns = 0;
        const int* dr = D + (size_t)w * Smax;
        for (int j = 0; j < Smax; ++j) ns += (dr[j] != 0);
        int lo = 0, hi = BB;
        while (hi - lo > 1) {
            int mid = (lo + hi) >> 1;
            if (ex_sub_off[mid] <= subrank) lo = mid; else hi = mid;
        }
        g_src[wb + w] = lo * LL + ex_f[lo] + (subrank - ex_sub_off[lo]);
        g_ns[wb + w] = ns;
        subrank += ns;
    }
}

// ---------------------------------------------------------------------------
// Means kernel: one block per word slot; mean over ns consecutive token rows,
// emit bf16 row into meansB.
// ---------------------------------------------------------------------------
__global__ __launch_bounds__(256)
void means_kernel(const float* __restrict__ X, const int* __restrict__ g_src,
                  const int* __restrict__ g_ns, const int* __restrict__ g_orow,
                  unsigned short* __restrict__ meansB)
{
    const int w = blockIdx.x;
    if (g_orow[w] < 0) return;
    const int ns = g_ns[w];
    const int base = g_src[w];
    const int c0 = threadIdx.x * 4;
    float ax = 0.f, ay = 0.f, az = 0.f, aw = 0.f;
    for (int j = 0; j < ns; ++j) {
        const float4 v = *reinterpret_cast<const float4*>(
            X + (size_t)(base + j) * HH + c0);
        ax += v.x; ay += v.y; az += v.z; aw += v.w;
    }
    const float s = 1.0f / (float)ns;
    ushort4 o;
    o.x = f2b(ax * s); o.y = f2b(ay * s); o.z = f2b(az * s); o.w = f2b(aw * s);
    *reinterpret_cast<ushort4*>(meansB + (size_t)w * HH + c0) = o;
}

// ---------------------------------------------------------------------------
// W fp32 -> bf16 conversion (row-major H x H).
// ---------------------------------------------------------------------------
__global__ __launch_bounds__(256)
void wconv_kernel(const float* __restrict__ Wf, unsigned short* __restrict__ Wb)
{
    const int idx = (blockIdx.x * 256 + threadIdx.x) * 4;
    const float4 v = *reinterpret_cast<const float4*>(Wf + idx);
    ushort4 o;
    o.x = f2b(v.x); o.y = f2b(v.y); o.z = f2b(v.z); o.w = f2b(v.w);
    *reinterpret_cast<ushort4*>(Wb + idx) = o;
}

// ---------------------------------------------------------------------------
// GEMM: C[w, o] = tanh( sum_h mean[w,h] * W[o,h] + b[o] ), scattered to
// out[g_orow[w], :]. Block = 256 thr = 4 waves; tile 64(M) x 64(N), BK=64:
// 8 MFMA per barrier pair (v1 had 4 with BK=32). B-tile 64x64 bf16 in LDS,
// stride 72 elems (144 B, 16B-aligned; worst 2-way bank aliasing = free).
// ---------------------------------------------------------------------------
__global__ __launch_bounds__(256)
void gemm_kernel(const unsigned short* __restrict__ A,
                 const unsigned short* __restrict__ Wb,
                 const float* __restrict__ bias,
                 const int* __restrict__ g_orow,
                 float* __restrict__ out, int M_total)
{
    __shared__ unsigned short lb[64 * 72];

    const int m_base = blockIdx.x * 64;
    const int n_base = blockIdx.y * 64;
    const int tid = threadIdx.x;
    const int wv = tid >> 6;
    const int lane = tid & 63;
    const int q = lane >> 4;     // quad id 0..3
    const int ml = lane & 15;

    const int row16 = m_base + wv * 16 + ml;
    const int orow_ml = (row16 < M_total) ? g_orow[row16] : -1;
    if (!__syncthreads_or(orow_ml >= 0)) return;   // whole 64-row stripe padded

    f32x4 acc[4];
    #pragma unroll
    for (int t = 0; t < 4; ++t) acc[t] = (f32x4){0.f, 0.f, 0.f, 0.f};

    // staging: thread -> (row 0..63, 16-elem chunk 0..3)
    const int srow = tid >> 2;
    const int schunk = tid & 3;
    const unsigned short* Bsrc = Wb + (size_t)(n_base + srow) * HH + schunk * 16;
    unsigned short* Bdst = lb + srow * 72 + schunk * 16;

    const unsigned short* Ap = A + (size_t)row16 * HH + q * 8;
    const unsigned short* l0 = lb + ml * 72 + q * 8;

    for (int k0 = 0; k0 < HH; k0 += 64) {
        __syncthreads();
        *reinterpret_cast<short8*>(Bdst) =
            *reinterpret_cast<const short8*>(Bsrc + k0);
        *reinterpret_cast<short8*>(Bdst + 8) =
            *reinterpret_cast<const short8*>(Bsrc + k0 + 8);
        __syncthreads();
        const short8 a0 = *reinterpret_cast<const short8*>(Ap + k0);
        const short8 a1 = *reinterpret_cast<const short8*>(Ap + k0 + 32);
        #pragma unroll
        for (int nq = 0; nq < 4; ++nq) {
            const short8 b0 = *reinterpret_cast<const short8*>(l0 + nq * 16 * 72);
            acc[nq] = __builtin_amdgcn_mfma_f32_16x16x32_bf16(a0, b0, acc[nq], 0, 0, 0);
        }
        #pragma unroll
        for (int nq = 0; nq < 4; ++nq) {
            const short8 b1 = *reinterpret_cast<const short8*>(l0 + nq * 16 * 72 + 32);
            acc[nq] = __builtin_amdgcn_mfma_f32_16x16x32_bf16(a1, b1, acc[nq], 0, 0, 0);
        }
    }

    // Epilogue: C/D layout col = lane&15, row = quad*4 + reg.
    #pragma unroll
    for (int t = 0; t < 4; ++t) {
        const int col = n_base + t * 16 + ml;
        const float bv = bias[col];
        #pragma unroll
        for (int r = 0; r < 4; ++r) {
            const int row = m_base + wv * 16 + q * 4 + r;
            if (row < M_total) {
                const int orow = g_orow[row];
                if (orow >= 0) {
                    out[(size_t)orow * HH + col] = tanhf(acc[t][r] + bv);
                }
            }
        }
    }
}

// ---------------------------------------------------------------------------
// Host launch
// Input order: 0..2 plm masks (B,L); 3..5 subword masks (NW,Smax);
// 6..8 word masks (flat); 9 inputs (B,L,H) f32; 10 W (H,H) f32; 11 b (H,).
// Output: concat of three word-mask-shaped (...,H) f32 tensors.
// ---------------------------------------------------------------------------
extern "C" void kernel_launch(void* const* d_in, const int* in_sizes, int n_in,
                              void* d_out, int out_size, void* d_ws, size_t ws_size,
                              hipStream_t stream)
{
    const int* plm0 = (const int*)d_in[0];
    const int* plm1 = (const int*)d_in[1];
    const int* plm2 = (const int*)d_in[2];
    const int* sub0 = (const int*)d_in[3];
    const int* sub1 = (const int*)d_in[4];
    const int* sub2 = (const int*)d_in[5];
    const int* wm0  = (const int*)d_in[6];
    const int* wm1  = (const int*)d_in[7];
    const int* wm2  = (const int*)d_in[8];
    const float* X    = (const float*)d_in[9];
    const float* Wf   = (const float*)d_in[10];
    const float* bias = (const float*)d_in[11];

    const int wmsz0 = in_sizes[6], wmsz1 = in_sizes[7], wmsz2 = in_sizes[8];
    const int cap0 = (wmsz0 + 63) & ~63;
    const int cap1 = (wmsz1 + 63) & ~63;
    const int cap2 = (wmsz2 + 63) & ~63;
    const int Mslots = cap0 + cap1 + cap2;   // multiple of 64
    const int gx = Mslots / 64;

    char* ws = (char*)d_ws;
    unsigned short* Wb = (unsigned short*)ws;                       // 2 MB
    unsigned short* meansB = (unsigned short*)(ws + (size_t)HH * HH * 2);
    char* p = ws + (size_t)HH * HH * 2 + (size_t)Mslots * HH * 2;
    int* g_src  = (int*)p; p += (size_t)Mslots * 4;
    int* g_ns   = (int*)p; p += (size_t)Mslots * 4;
    int* g_orow = (int*)p;

    hipMemsetAsync(d_out, 0, (size_t)out_size * sizeof(float), stream);

    wconv_kernel<<<(HH * HH / 4) / 256, 256, 0, stream>>>(Wf, Wb);

    meta_kernel<<<3, 256, 0, stream>>>(plm0, plm1, plm2, sub0, sub1, sub2,
                                       wm0, wm1, wm2,
                                       in_sizes[3], in_sizes[4], in_sizes[5],
                                       wmsz0, wmsz1, wmsz2,
                                       cap0, cap1, cap2,
                                       g_src, g_ns, g_orow);

    means_kernel<<<Mslots, 256, 0, stream>>>(X, g_src, g_ns, g_orow, meansB);

    gemm_kernel<<<dim3(gx, 16), 256, 0, stream>>>(meansB, Wb, bias, g_orow,
                                                  (float*)d_out, Mslots);
}

// Round 4
// 276.138 us; speedup vs baseline: 1.1597x; 1.0182x over previous
//
#include <hip/hip_runtime.h>
#include <hip/hip_bf16.h>
#include <stdint.h>

// Problem constants (reference: B, L, H = 64, 512, 1024)
#define BB 64
#define LL 512
#define HH 1024

using short8 = __attribute__((ext_vector_type(8))) short;
using f32x4  = __attribute__((ext_vector_type(4))) float;

static __device__ __forceinline__ unsigned short f2b(float x) {
    union { float f; uint32_t u; } t; t.f = x;
    uint32_t u = t.u;
    u += 0x7fffu + ((u >> 16) & 1u);   // round-to-nearest-even
    return (unsigned short)(u >> 16);
}

// ---------------------------------------------------------------------------
// K1: blocks 0..2 = meta decode (one per category); blocks 3+ = W fp32->bf16.
// Meta semantics (verified in R2/R3 passing runs):
//  - PLM mask (B,L): contiguous span per example; r-th True = global subword r
//  - word mask (flat wmsz): k-th True at flat pos p -> word k -> output row
//    rbase+p. We store the inverse map g_wrow[rbase+p] = word slot (wb+k),
//    and -1 for non-True rows (GEMM writes zeros there; no memset needed).
//  - subword mask (NW,Smax): row w has ns_w leading Trues; Smax = ssub/NW
// Word-slot outputs: g_src[wb+w] = first-subword flat token idx, g_ns = count
// (g_ns==0 marks padding slots for the means kernel).
// ---------------------------------------------------------------------------
__global__ __launch_bounds__(256)
void meta_kernel(const int* __restrict__ plm0, const int* __restrict__ plm1,
                 const int* __restrict__ plm2,
                 const int* __restrict__ sub0, const int* __restrict__ sub1,
                 const int* __restrict__ sub2,
                 const int* __restrict__ wm0, const int* __restrict__ wm1,
                 const int* __restrict__ wm2,
                 int ssub0, int ssub1, int ssub2,
                 int wmsz0, int wmsz1, int wmsz2,
                 int cap0, int cap1, int cap2,
                 const float* __restrict__ Wf, unsigned short* __restrict__ Wb,
                 int* __restrict__ g_src, int* __restrict__ g_ns,
                 int* __restrict__ g_wrow)
{
    const int tid = threadIdx.x;

    // ---- wconv blocks: convert W (H*H fp32) to bf16, 4 elems/thread.
    if (blockIdx.x >= 3) {
        const int idx = ((blockIdx.x - 3) * 256 + tid) * 4;
        const float4 v = *reinterpret_cast<const float4*>(Wf + idx);
        ushort4 o;
        o.x = f2b(v.x); o.y = f2b(v.y); o.z = f2b(v.z); o.w = f2b(v.w);
        *reinterpret_cast<ushort4*>(Wb + idx) = o;
        return;
    }

    const int cat = blockIdx.x;
    const int* P    = (cat == 0) ? plm0 : (cat == 1) ? plm1 : plm2;
    const int* D    = (cat == 0) ? sub0 : (cat == 1) ? sub1 : sub2;
    const int* WM   = (cat == 0) ? wm0  : (cat == 1) ? wm1  : wm2;
    const int ssub  = (cat == 0) ? ssub0 : (cat == 1) ? ssub1 : ssub2;
    const int wmsz  = (cat == 0) ? wmsz0 : (cat == 1) ? wmsz1 : wmsz2;
    const int cap   = (cat == 0) ? cap0  : (cat == 1) ? cap1  : cap2;
    int wb = 0, rbase = 0;
    if (cat >= 1) { wb += cap0; rbase += wmsz0; }
    if (cat >= 2) { wb += cap1; rbase += wmsz1; }

    __shared__ int ex_f[BB];
    __shared__ int ex_sub_off[BB + 1];
    __shared__ int qf[256], qc[256];
    __shared__ int wsum[4];

    const int lane = tid & 63;
    const int wv = tid >> 6;

    // ---- Stage 1: PLM per-example first-True + count; (row, quarter) split.
    {
        const int row = tid & 63;
        const int quarter = tid >> 6;
        const int4* rp = reinterpret_cast<const int4*>(P + row * LL + quarter * 128);
        int c = 0, f = 0x7fffffff;
        #pragma unroll 8
        for (int i = 0; i < 32; ++i) {
            int4 v = rp[i];
            if (v.x) { ++c; if (f == 0x7fffffff) f = quarter * 128 + i * 4 + 0; }
            if (v.y) { ++c; if (f == 0x7fffffff) f = quarter * 128 + i * 4 + 1; }
            if (v.z) { ++c; if (f == 0x7fffffff) f = quarter * 128 + i * 4 + 2; }
            if (v.w) { ++c; if (f == 0x7fffffff) f = quarter * 128 + i * 4 + 3; }
        }
        qc[tid] = c;
        qf[tid] = f;
    }
    __syncthreads();
    if (tid < 64) {   // wave 0 only
        int c = qc[tid] + qc[tid + 64] + qc[tid + 128] + qc[tid + 192];
        int f = min(min(qf[tid], qf[tid + 64]), min(qf[tid + 128], qf[tid + 192]));
        ex_f[tid] = (f == 0x7fffffff) ? 0 : f;
        int v = c;
        #pragma unroll
        for (int off = 1; off < 64; off <<= 1) {
            int u = __shfl_up(v, off, 64);
            if (tid >= off) v += u;
        }
        ex_sub_off[tid + 1] = v;
        if (tid == 0) ex_sub_off[0] = 0;
    }

    // Default-fill inverse row map for this category's row range.
    for (int p = tid; p < wmsz; p += 256) g_wrow[rbase + p] = -1;
    __syncthreads();

    // ---- Pass A: word-mask flat scan. Thread-contiguous segments.
    const int seg = (wmsz + 255) >> 8;
    const int p0 = tid * seg;
    const int p1 = min(p0 + seg, wmsz);
    int c = 0;
    for (int p = p0; p < p1; ++p) c += (WM[p] != 0);
    int incl = c;
    #pragma unroll
    for (int off = 1; off < 64; off <<= 1) {
        int u = __shfl_up(incl, off, 64);
        if (lane >= off) incl += u;
    }
    if (lane == 63) wsum[wv] = incl;
    __syncthreads();
    int woff = 0;
    for (int i = 0; i < wv; ++i) woff += wsum[i];
    const int NW = wsum[0] + wsum[1] + wsum[2] + wsum[3];
    int k = woff + incl - c;      // exclusive rank of first True in my segment
    for (int p = p0; p < p1; ++p)
        if (WM[p]) g_wrow[rbase + p] = wb + (k++);

    // Padding word slots (g_ns==0 marks dead).
    for (int w = NW + tid; w < cap; w += 256) {
        g_ns[wb + w] = 0;
        g_src[wb + w] = 0;
    }

    const int Smax = (NW > 0) ? (ssub / NW) : 1;

    // ---- Pass B: per-word subword counts -> g_src, g_ns.
    const int seg2 = (NW + 255) >> 8;
    const int w0 = tid * seg2;
    const int w1 = min(w0 + seg2, NW);
    int cs = 0;
    for (int w = w0; w < w1; ++w) {
        const int* dr = D + (size_t)w * Smax;
        for (int j = 0; j < Smax; ++j) cs += (dr[j] != 0);
    }
    __syncthreads();              // wsum reuse: all Pass-A reads are done
    int incl2 = cs;
    #pragma unroll
    for (int off = 1; off < 64; off <<= 1) {
        int u = __shfl_up(incl2, off, 64);
        if (lane >= off) incl2 += u;
    }
    if (lane == 63) wsum[wv] = incl2;
    __syncthreads();
    int soff = 0;
    for (int i = 0; i < wv; ++i) soff += wsum[i];
    int subrank = soff + incl2 - cs;
    for (int w = w0; w < w1; ++w) {
        int ns = 0;
        const int* dr = D + (size_t)w * Smax;
        for (int j = 0; j < Smax; ++j) ns += (dr[j] != 0);
        int lo = 0, hi = BB;
        while (hi - lo > 1) {
            int mid = (lo + hi) >> 1;
            if (ex_sub_off[mid] <= subrank) lo = mid; else hi = mid;
        }
        g_src[wb + w] = lo * LL + ex_f[lo] + (subrank - ex_sub_off[lo]);
        g_ns[wb + w] = ns;
        subrank += ns;
    }
}

// ---------------------------------------------------------------------------
// K2: means. 4 word slots per block (one per wave); mean over ns consecutive
// token rows of X, emit bf16 row into meansB. Dead slots (ns==0) skipped.
// ---------------------------------------------------------------------------
__global__ __launch_bounds__(256)
void means_kernel(const float* __restrict__ X, const int* __restrict__ g_src,
                  const int* __restrict__ g_ns,
                  unsigned short* __restrict__ meansB)
{
    const int w = blockIdx.x * 4 + (threadIdx.x >> 6);
    const int lane = threadIdx.x & 63;
    const int ns = g_ns[w];
    if (ns == 0) return;
    const int base = g_src[w];
    float4 acc[4] = {{0,0,0,0},{0,0,0,0},{0,0,0,0},{0,0,0,0}};
    for (int j = 0; j < ns; ++j) {
        const float4* xp = reinterpret_cast<const float4*>(
            X + (size_t)(base + j) * HH) + lane;
        #pragma unroll
        for (int ch = 0; ch < 4; ++ch) {
            const float4 v = xp[ch * 64];
            acc[ch].x += v.x; acc[ch].y += v.y; acc[ch].z += v.z; acc[ch].w += v.w;
        }
    }
    const float s = 1.0f / (float)ns;
    ushort4* mp = reinterpret_cast<ushort4*>(meansB + (size_t)w * HH) + lane;
    #pragma unroll
    for (int ch = 0; ch < 4; ++ch) {
        ushort4 o;
        o.x = f2b(acc[ch].x * s); o.y = f2b(acc[ch].y * s);
        o.z = f2b(acc[ch].z * s); o.w = f2b(acc[ch].w * s);
        mp[ch * 64] = o;
    }
}

// ---------------------------------------------------------------------------
// K3: GEMM over OUTPUT rows. out[p,o] = (g_wrow[p]>=0)
//   ? tanh( sum_h mean[g_wrow[p],h] * W[o,h] + b[o] ) : 0.
// Block 256 = 4 waves; tile 64(rows) x 64(N), BK=64, 8 MFMA/barrier-pair.
// B-tile in LDS stride 72 (2-way bank aliasing = free). A rows gathered
// directly from global with per-lane indirection. Dead 64-row stripes take a
// store-only fast path. Writes ALL rows -> replaces the d_out memset.
// ---------------------------------------------------------------------------
__global__ __launch_bounds__(256)
void gemm_kernel(const unsigned short* __restrict__ A,
                 const unsigned short* __restrict__ Wb,
                 const float* __restrict__ bias,
                 const int* __restrict__ g_wrow,
                 float* __restrict__ out, int rows_total)
{
    __shared__ unsigned short lb[64 * 72];

    const int m_base = blockIdx.x * 64;
    const int n_base = blockIdx.y * 64;
    const int tid = threadIdx.x;
    const int wv = tid >> 6;
    const int lane = tid & 63;
    const int q = lane >> 4;     // quad id 0..3
    const int ml = lane & 15;

    const int row16 = m_base + wv * 16 + ml;
    int arow = (row16 < rows_total) ? g_wrow[row16] : -1;
    if (!__syncthreads_or(arow >= 0)) {
        // dead stripe: zeros only. 4 threads/row, 16 cols each.
        const int zr = m_base + (tid >> 2);
        if (zr < rows_total) {
            float4 z = {0.f, 0.f, 0.f, 0.f};
            float4* o = reinterpret_cast<float4*>(
                out + (size_t)zr * HH + n_base + (tid & 3) * 16);
            o[0] = z; o[1] = z; o[2] = z; o[3] = z;
        }
        return;
    }
    if (arow < 0) arow = 0;   // dead lane in live stripe: any valid row

    f32x4 acc[4];
    #pragma unroll
    for (int t = 0; t < 4; ++t) acc[t] = (f32x4){0.f, 0.f, 0.f, 0.f};

    // staging: thread -> (row 0..63, 16-elem chunk 0..3)
    const int srow_st = tid >> 2;
    const int schunk = tid & 3;
    const unsigned short* Bsrc = Wb + (size_t)(n_base + srow_st) * HH + schunk * 16;
    unsigned short* Bdst = lb + srow_st * 72 + schunk * 16;

    const unsigned short* Ap = A + (size_t)arow * HH + q * 8;
    const unsigned short* l0 = lb + ml * 72 + q * 8;

    for (int k0 = 0; k0 < HH; k0 += 64) {
        __syncthreads();
        *reinterpret_cast<short8*>(Bdst) =
            *reinterpret_cast<const short8*>(Bsrc + k0);
        *reinterpret_cast<short8*>(Bdst + 8) =
            *reinterpret_cast<const short8*>(Bsrc + k0 + 8);
        __syncthreads();
        const short8 a0 = *reinterpret_cast<const short8*>(Ap + k0);
        const short8 a1 = *reinterpret_cast<const short8*>(Ap + k0 + 32);
        #pragma unroll
        for (int nq = 0; nq < 4; ++nq) {
            const short8 b0 = *reinterpret_cast<const short8*>(l0 + nq * 16 * 72);
            acc[nq] = __builtin_amdgcn_mfma_f32_16x16x32_bf16(a0, b0, acc[nq], 0, 0, 0);
        }
        #pragma unroll
        for (int nq = 0; nq < 4; ++nq) {
            const short8 b1 = *reinterpret_cast<const short8*>(l0 + nq * 16 * 72 + 32);
            acc[nq] = __builtin_amdgcn_mfma_f32_16x16x32_bf16(a1, b1, acc[nq], 0, 0, 0);
        }
    }

    // Epilogue: C/D layout col = lane&15, row = quad*4 + reg. Dense writes.
    float bv[4];
    #pragma unroll
    for (int t = 0; t < 4; ++t) bv[t] = bias[n_base + t * 16 + ml];
    #pragma unroll
    for (int r = 0; r < 4; ++r) {
        const int srow = m_base + wv * 16 + q * 4 + r;
        if (srow < rows_total) {
            const int wr = g_wrow[srow];
            #pragma unroll
            for (int t = 0; t < 4; ++t) {
                const int col = n_base + t * 16 + ml;
                out[(size_t)srow * HH + col] =
                    (wr >= 0) ? tanhf(acc[t][r] + bv[t]) : 0.0f;
            }
        }
    }
}

// ---------------------------------------------------------------------------
// Host launch. Inputs: 0..2 plm (B,L); 3..5 subword (NW,Smax); 6..8 word
// masks (flat); 9 X (B,L,H) f32; 10 W (H,H) f32; 11 b (H,) f32.
// Output: concat of three word-mask-shaped (...,H) f32 tensors (dense).
// ---------------------------------------------------------------------------
extern "C" void kernel_launch(void* const* d_in, const int* in_sizes, int n_in,
                              void* d_out, int out_size, void* d_ws, size_t ws_size,
                              hipStream_t stream)
{
    const int* plm0 = (const int*)d_in[0];
    const int* plm1 = (const int*)d_in[1];
    const int* plm2 = (const int*)d_in[2];
    const int* sub0 = (const int*)d_in[3];
    const int* sub1 = (const int*)d_in[4];
    const int* sub2 = (const int*)d_in[5];
    const int* wm0  = (const int*)d_in[6];
    const int* wm1  = (const int*)d_in[7];
    const int* wm2  = (const int*)d_in[8];
    const float* X    = (const float*)d_in[9];
    const float* Wf   = (const float*)d_in[10];
    const float* bias = (const float*)d_in[11];

    const int wmsz0 = in_sizes[6], wmsz1 = in_sizes[7], wmsz2 = in_sizes[8];
    const int cap0 = (wmsz0 + 63) & ~63;
    const int cap1 = (wmsz1 + 63) & ~63;
    const int cap2 = (wmsz2 + 63) & ~63;
    const int Mslots = cap0 + cap1 + cap2;        // word-slot capacity (x64)
    const int rows_total = wmsz0 + wmsz1 + wmsz2; // output rows
    const int gx = (rows_total + 63) / 64;

    char* ws = (char*)d_ws;
    unsigned short* Wb = (unsigned short*)ws;                       // 2 MB
    unsigned short* meansB = (unsigned short*)(ws + (size_t)HH * HH * 2);
    char* p = ws + (size_t)HH * HH * 2 + (size_t)Mslots * HH * 2;
    int* g_src  = (int*)p; p += (size_t)Mslots * 4;
    int* g_ns   = (int*)p; p += (size_t)Mslots * 4;
    int* g_wrow = (int*)p;

    meta_kernel<<<3 + (HH * HH / 4) / 256, 256, 0, stream>>>(
        plm0, plm1, plm2, sub0, sub1, sub2, wm0, wm1, wm2,
        in_sizes[3], in_sizes[4], in_sizes[5],
        wmsz0, wmsz1, wmsz2, cap0, cap1, cap2,
        Wf, Wb, g_src, g_ns, g_wrow);

    means_kernel<<<Mslots / 4, 256, 0, stream>>>(X, g_src, g_ns, meansB);

    gemm_kernel<<<dim3(gx, 16), 256, 0, stream>>>(meansB, Wb, bias, g_wrow,
                                                  (float*)d_out, rows_total);
}